// Round 1
// baseline (721.315 us; speedup 1.0000x reference)
//
#include <hip/hip_runtime.h>
#include <hip/hip_bf16.h>
#include <math.h>

#define NROWS 8192
#define DIM   1024
#define CAP   256
#define MARGIN 120.0f

using f16x8 = __attribute__((ext_vector_type(8))) _Float16;
using f32x4 = __attribute__((ext_vector_type(4))) float;
typedef unsigned short u16;
typedef unsigned int   u32;

#define AS1 __attribute__((address_space(1)))
#define AS3 __attribute__((address_space(3)))

// ---------------- split fp32 array (len % 1024 == 0) into hi/lo fp16 planes ----
// fp16 2-split carries ~22 mantissa bits: hi + lo with lo = fp16(x - (float)hi).
__global__ __launch_bounds__(256) void split2h(const float* __restrict__ X,
                                               u16* __restrict__ H,
                                               u16* __restrict__ L) {
    const int idx = (blockIdx.x * 256 + threadIdx.x) * 4;
    float4 x = *(const float4*)&X[idx];
    float c[4] = {x.x, x.y, x.z, x.w};
    u16 h[4], l[4];
#pragma unroll
    for (int i = 0; i < 4; ++i) {
        _Float16 hh = (_Float16)c[i];
        float r = c[i] - (float)hh;
        _Float16 ll = (_Float16)r;
        h[i] = *(u16*)&hh; l[i] = *(u16*)&ll;
    }
    *(ushort4*)&H[idx] = make_ushort4(h[0], h[1], h[2], h[3]);
    *(ushort4*)&L[idx] = make_ushort4(l[0], l[1], l[2], l[3]);
}

// ---------------- transpose Wv, keep hi fp16 plane: Wvth[c][d] = f16(Wv[d][c]) -
__global__ __launch_bounds__(256) void split_wvt(const float* __restrict__ W,
                                                 u16* __restrict__ H) {
    __shared__ float t[64][65];
    const int k0 = blockIdx.x * 64, n0 = blockIdx.y * 64;
    const int c = threadIdx.x & 63, r4 = threadIdx.x >> 6;
#pragma unroll
    for (int i = 0; i < 16; ++i) {
        int k = r4 + i * 4;
        t[k][c] = W[(size_t)(k0 + k) * DIM + n0 + c];
    }
    __syncthreads();
#pragma unroll
    for (int i = 0; i < 16; ++i) {
        int n = r4 + i * 4;
        _Float16 hb = (_Float16)t[c][n];
        H[(n0 + n) * DIM + k0 + c] = *(u16*)&hb;
    }
}

// ---------------- OLD shared LDS-dbuf 128x128 NT fp16 GEMM engine (g_gemm only)
template<int NP>
__device__ __forceinline__ void gemm_lds(const u16* const (&Ap)[NP],
                                         const u16* const (&Bp)[NP],
                                         int row0, int col0, f32x4 (&acc)[4][4],
                                         short (&As)[2][2][4096], short (&Bs)[2][2][4096]) {
    const int tid = threadIdx.x;
    const int w = tid >> 6, lane = tid & 63;
    const int wy = w >> 1, wx = w & 1;
    const int quad = lane >> 4, r16 = lane & 15;

    const int    srow   = w * 32 + (lane >> 2);
    const int    schunk = (lane & 3) * 8;
    const size_t gA0 = (size_t)(row0 + srow) * DIM + schunk;
    const size_t gA1 = gA0 + (size_t)16 * DIM;
    const size_t gB0 = (size_t)(col0 + srow) * DIM + schunk;
    const size_t gB1 = gB0 + (size_t)16 * DIM;
    const int lds0 = (w * 32) * 32;
    const int lds1 = (w * 32 + 16) * 32;

    auto issue = [&](const u16* A, const u16* B, size_t k0, int buf) {
#pragma unroll
        for (int s = 0; s < 2; ++s) {
            const size_t ko = k0 + (size_t)s * 32;
            __builtin_amdgcn_global_load_lds((const AS1 u32*)(A + gA0 + ko), (AS3 u32*)&As[buf][s][lds0], 16, 0, 0);
            __builtin_amdgcn_global_load_lds((const AS1 u32*)(A + gA1 + ko), (AS3 u32*)&As[buf][s][lds1], 16, 0, 0);
            __builtin_amdgcn_global_load_lds((const AS1 u32*)(B + gB0 + ko), (AS3 u32*)&Bs[buf][s][lds0], 16, 0, 0);
            __builtin_amdgcn_global_load_lds((const AS1 u32*)(B + gB1 + ko), (AS3 u32*)&Bs[buf][s][lds1], 16, 0, 0);
        }
    };

    issue(Ap[0], Bp[0], 0, 0);

    int pp = 0;
#pragma unroll
    for (int p = 0; p < NP; ++p) {
        const u16* A = Ap[p];
        const u16* B = Bp[p];
        const u16* An = (p + 1 < NP) ? Ap[p + 1] : A;
        const u16* Bn = (p + 1 < NP) ? Bp[p + 1] : B;
        const bool more = (p + 1 < NP);
        for (int i = 0; i < 16; ++i) {
            __syncthreads();
            const int cur = pp, nxt = pp ^ 1;
            if (i < 15)      issue(A, B, (size_t)(i + 1) * 64, nxt);
            else if (more)   issue(An, Bn, 0, nxt);
#pragma unroll
            for (int s = 0; s < 2; ++s) {
                const short* AsC = As[cur][s];
                const short* BsC = Bs[cur][s];
                f16x8 af[4], bfr[4];
#pragma unroll
                for (int m = 0; m < 4; ++m)
                    af[m] = *(const f16x8*)&AsC[(wy * 64 + m * 16 + r16) * 32 + quad * 8];
#pragma unroll
                for (int n = 0; n < 4; ++n)
                    bfr[n] = *(const f16x8*)&BsC[(wx * 64 + n * 16 + r16) * 32 + quad * 8];
#pragma unroll
                for (int m = 0; m < 4; ++m)
#pragma unroll
                    for (int n = 0; n < 4; ++n)
                        acc[m][n] = __builtin_amdgcn_mfma_f32_16x16x32_f16(af[m], bfr[n], acc[m][n], 0, 0, 0);
            }
            pp ^= 1;
        }
    }
}

// ---------------- NEW 256x256 NT fp16 engine, BK=32, 4-deep LDS pipeline ------
// 512 thr / 8 waves (2 x 4); each wave owns a 128x64 C tile via 8x4 of
// 16x16x32 f16 MFMA. Four 32-KiB K-step LDS buffers (128 KiB total): while
// computing K-step t from buf[t%4], stage K-step t+3 into buf[(t+3)%4]
// (that buffer was last read at t-1, ordered by the barrier). Counted
// `s_waitcnt vmcnt(8)` + raw s_barrier keeps 2 K-steps (8 loads) in flight
// ACROSS the barrier -- never drains to 0 in steady state (T3/T4).
// LDS swizzle (T2): 16B chunk index c stored at slot c ^ ((row>>1)&3); the
// global SOURCE address is pre-swizzled (global_load_lds dest must stay
// linear, rule #21) -- per-lane src chunk = (lane&3) ^ ((lane>>3)&3). The
// ds_read_b128 side reads slot quad ^ ((r16>>1)&3): each 16-lane phase then
// touches all 8 bank granules evenly (2 lanes each) instead of 2 (8-way).
template<int NP>
__device__ __forceinline__ void gemm256(const u16* const (&Ap)[NP],
                                        const u16* const (&Bp)[NP],
                                        int row0, int col0, f32x4 (&acc)[8][4],
                                        short (&As)[4][8192], short (&Bs)[4][8192]) {
    const int tid = threadIdx.x;
    const int w = tid >> 6, lane = tid & 63;
    const int wy = w >> 2, wx = w & 3;
    const int quad = lane >> 4, r16 = lane & 15;

    // staging: per K-step 4 global_load_lds/thread; line l covers tile rows
    // l*128..l*128+127, wave w rows w*16..w*16+15; LDS dest is linear
    // (slot = tid*16B), source chunk pre-swizzled.
    const int srow   = w * 16 + (lane >> 2);
    const int schunk = ((lane & 3) ^ ((lane >> 3) & 3)) * 8;
    const size_t gA0 = (size_t)(row0 + srow) * DIM + schunk;
    const size_t gA1 = gA0 + (size_t)128 * DIM;
    const size_t gB0 = (size_t)(col0 + srow) * DIM + schunk;
    const size_t gB1 = gB0 + (size_t)128 * DIM;
    const int lds0 = w * 512;          // shorts, wave base line 0
    const int lds1 = 4096 + w * 512;   // shorts, wave base line 1

    auto stage = [&](int kt, int buf) {
        const u16* A = Ap[(NP > 1) ? (kt >> 5) : 0];
        const u16* B = Bp[(NP > 1) ? (kt >> 5) : 0];
        const size_t ko = (size_t)(kt & 31) * 32;
        __builtin_amdgcn_global_load_lds((const AS1 u32*)(A + gA0 + ko), (AS3 u32*)&As[buf][lds0], 16, 0, 0);
        __builtin_amdgcn_global_load_lds((const AS1 u32*)(A + gA1 + ko), (AS3 u32*)&As[buf][lds1], 16, 0, 0);
        __builtin_amdgcn_global_load_lds((const AS1 u32*)(B + gB0 + ko), (AS3 u32*)&Bs[buf][lds0], 16, 0, 0);
        __builtin_amdgcn_global_load_lds((const AS1 u32*)(B + gB1 + ko), (AS3 u32*)&Bs[buf][lds1], 16, 0, 0);
    };

    const int ccol = (quad ^ ((r16 >> 1) & 3)) * 8;  // swizzled 16B chunk
    const int arow = wy * 128 + r16;                 // + m*16
    const int brow = wx * 64  + r16;                 // + n*16

    auto compute = [&](int buf) {
        f16x8 af[8], bf[4];
#pragma unroll
        for (int m = 0; m < 8; ++m)
            af[m] = *(const f16x8*)&As[buf][(arow + m * 16) * 32 + ccol];
#pragma unroll
        for (int n = 0; n < 4; ++n)
            bf[n] = *(const f16x8*)&Bs[buf][(brow + n * 16) * 32 + ccol];
        asm volatile("s_waitcnt lgkmcnt(0)" ::: "memory");
        __builtin_amdgcn_sched_barrier(0);
        __builtin_amdgcn_s_setprio(1);
#pragma unroll
        for (int m = 0; m < 8; ++m)
#pragma unroll
            for (int n = 0; n < 4; ++n)
                acc[m][n] = __builtin_amdgcn_mfma_f32_16x16x32_f16(af[m], bf[n], acc[m][n], 0, 0, 0);
        __builtin_amdgcn_s_setprio(0);
        __builtin_amdgcn_sched_barrier(0);
    };

    constexpr int NK = NP * 32;
    stage(0, 0); stage(1, 1); stage(2, 2);   // 12 loads in flight
#pragma unroll 1
    for (int t = 0; t < NK - 2; ++t) {
        // 12 outstanding -> wait to 8: oldest 4 (K-step t) have landed.
        asm volatile("s_waitcnt vmcnt(8)" ::: "memory");
        __builtin_amdgcn_s_barrier();          // all waves' K-step t visible
        asm volatile("" ::: "memory");
        if (t < NK - 3) stage(t + 3, (t + 3) & 3);
        compute(t & 3);
    }
    asm volatile("s_waitcnt vmcnt(4)" ::: "memory");   // t = NK-2: 8 -> 4
    __builtin_amdgcn_s_barrier();
    asm volatile("" ::: "memory");
    compute((NK - 2) & 3);
    asm volatile("s_waitcnt vmcnt(0)" ::: "memory");   // t = NK-1: drain
    __builtin_amdgcn_s_barrier();
    asm volatile("" ::: "memory");
    compute((NK - 1) & 3);
}

// ---------------- Gt = Wk @ Wq^T (fp32 out, Gt[c][d] = (Wq Wk^T)[d][c]) --------
// fp16 2-split: 3 products {lh, hl, hh} carry ~22 bits (ll dropped, rel 2^-22).
__global__ __launch_bounds__(256) void g_gemm(const u16* __restrict__ Wkh, const u16* __restrict__ Wkl,
                                              const u16* __restrict__ Wqh, const u16* __restrict__ Wql,
                                              float* __restrict__ Gt) {
    __shared__ short As[2][2][4096], Bs[2][2][4096];
    const int tid = threadIdx.x, w = tid >> 6, lane = tid & 63;
    const int wy = w >> 1, wx = w & 1, quad = lane >> 4, r16 = lane & 15;
    const int row0 = blockIdx.y * 128, col0 = blockIdx.x * 128;
    const u16* const Ap[3] = { Wkl, Wkh, Wkh };   // lh, hl, hh (small -> large)
    const u16* const Bp[3] = { Wqh, Wql, Wqh };
    f32x4 acc[4][4] = {};
    gemm_lds<3>(Ap, Bp, row0, col0, acc, As, Bs);
#pragma unroll
    for (int m = 0; m < 4; ++m)
#pragma unroll
        for (int n = 0; n < 4; ++n)
#pragma unroll
            for (int reg = 0; reg < 4; ++reg) {
                const int row = row0 + wy * 64 + m * 16 + quad * 4 + reg;
                const int col = col0 + wx * 64 + n * 16 + r16;
                Gt[row * DIM + col] = acc[m][n][reg];
            }
}

// ---------------- part0: Y = X@G (fp32+fp16) ; part1: Vh = Xh@Wvt_h -----------
// 256 blocks of 512 thr = exactly 1 block/CU, one full-GPU round.
__global__ __launch_bounds__(512, 2) void yv_gemm(const u16* __restrict__ Xh, const u16* __restrict__ Xl,
                                                  const u16* __restrict__ Gth, const u16* __restrict__ Gtl,
                                                  const u16* __restrict__ Wvth,
                                                  float* __restrict__ Y, u16* __restrict__ Yh, u16* __restrict__ Vh) {
    __shared__ short As[4][8192], Bs[4][8192];
    const int tid = threadIdx.x, w = tid >> 6, lane = tid & 63;
    const int wy = w >> 2, wx = w & 3, quad = lane >> 4, r16 = lane & 15;
    const int id = blockIdx.x;
    const int part = id >> 7;              // 0: Y (K_eff=3072), 1: V (K=1024)
    const int within = id & 127;
    const int rowt = within >> 2, colt = within & 3;
    const int row0 = rowt * 256, col0 = colt * 256;
    f32x4 acc[8][4] = {};
    if (part == 0) {
        const u16* const Ap[3] = { Xl,  Xh,  Xh  };   // lh, hl, hh
        const u16* const Bp[3] = { Gth, Gtl, Gth };
        gemm256<3>(Ap, Bp, row0, col0, acc, As, Bs);
#pragma unroll
        for (int m = 0; m < 8; ++m)
#pragma unroll
            for (int n = 0; n < 4; ++n)
#pragma unroll
                for (int reg = 0; reg < 4; ++reg) {
                    const int row = row0 + wy * 128 + m * 16 + quad * 4 + reg;
                    const int col = col0 + wx * 64 + n * 16 + r16;
                    float v = acc[m][n][reg];
                    Y[(size_t)row * DIM + col] = v;
                    _Float16 hb = (_Float16)v;
                    Yh[(size_t)row * DIM + col] = *(u16*)&hb;
                }
    } else {
        const u16* const Ap[1] = { Xh };
        const u16* const Bp[1] = { Wvth };
        gemm256<1>(Ap, Bp, row0, col0, acc, As, Bs);
#pragma unroll
        for (int m = 0; m < 8; ++m)
#pragma unroll
            for (int n = 0; n < 4; ++n)
#pragma unroll
                for (int reg = 0; reg < 4; ++reg) {
                    const int row = row0 + wy * 128 + m * 16 + quad * 4 + reg;
                    const int col = col0 + wx * 64 + n * 16 + r16;
                    _Float16 hb = (_Float16)acc[m][n][reg];
                    Vh[(size_t)row * DIM + col] = *(u16*)&hb;
                }
    }
}

// ---------------- filter: S = Yh @ Xh^T (fp16), per-64col-group margin emit ----
// 1024 blocks of 512 thr = 32x32 tiles of 256x256. XCD map: 4 Xh col-panels
// pinned per XCD L2, Yh row panels stream (shared by the 4 concurrent
// same-rowt blocks of each XCD). Margin semantics identical to the proven
// version: group = one wave's 64 cols; the group max is always emitted.
__global__ __launch_bounds__(512, 2) void filter_kernel(const u16* __restrict__ Yhp,
                                                        const u16* __restrict__ Xhp,
                                                        int* __restrict__ cnt,
                                                        int2* __restrict__ cand) {
    __shared__ short As[4][8192], Bs[4][8192];
    const int tid = threadIdx.x, w = tid >> 6, lane = tid & 63;
    const int wy = w >> 2, wx = w & 3, quad = lane >> 4, r16 = lane & 15;
    const int id = blockIdx.x;
    const int xcd = id & 7, within = id >> 3;
    const int colt = (xcd << 2) | (within & 3);   // 0..31, 4 per XCD
    const int rowt = within >> 2;                  // 0..31
    const int row0 = rowt << 8, col0 = colt << 8;

    const u16* const Ap[1] = { Yhp };
    const u16* const Bp[1] = { Xhp };
    f32x4 acc[8][4] = {};
    gemm256<1>(Ap, Bp, row0, col0, acc, As, Bs);

    // per row: 64-col group max -> margin filter -> emit (mechanics proven)
#pragma unroll
    for (int m = 0; m < 8; ++m) {
#pragma unroll
        for (int reg = 0; reg < 4; ++reg) {
            float mx = fmaxf(fmaxf(acc[m][0][reg], acc[m][1][reg]),
                             fmaxf(acc[m][2][reg], acc[m][3][reg]));
            mx = fmaxf(mx, __shfl_xor(mx, 1, 64));
            mx = fmaxf(mx, __shfl_xor(mx, 2, 64));
            mx = fmaxf(mx, __shfl_xor(mx, 4, 64));
            mx = fmaxf(mx, __shfl_xor(mx, 8, 64));
            const float th = mx - MARGIN;
            const int row = row0 + wy * 128 + m * 16 + quad * 4 + reg;
#pragma unroll
            for (int n = 0; n < 4; ++n) {
                float s = acc[m][n][reg];
                if (s >= th) {
                    int pos = atomicAdd(&cnt[row], 1);
                    if (pos < CAP)
                        cand[(size_t)row * CAP + pos] =
                            make_int2(col0 + wx * 64 + n * 16 + r16, __float_as_int(s));
                }
            }
        }
    }
}

// ---------------- finalize: refilter, fp64 rescore via Y·X, softmax, gather Vh -
__global__ __launch_bounds__(256) void finalize_kernel(const float* __restrict__ Y,
                                                       const float* __restrict__ X,
                                                       const u16* __restrict__ Vh,
                                                       const int* __restrict__ cnt,
                                                       const int2* __restrict__ cand,
                                                       float* __restrict__ out) {
    const int i = blockIdx.x;
    const int tid = threadIdx.x;
    const int w = tid >> 6, lane = tid & 63;
    __shared__ float  red[256];
    __shared__ int    surv[64];
    __shared__ double sprec[64];
    __shared__ float  wgt[64];
    __shared__ int    nsurv;

    const int c = min(cnt[i], CAP);
    float m = -3.0e38f;
    for (int t = tid; t < c; t += 256)
        m = fmaxf(m, __int_as_float(cand[(size_t)i * CAP + t].y));
    red[tid] = m;
    __syncthreads();
    for (int s = 128; s > 0; s >>= 1) {
        if (tid < s) red[tid] = fmaxf(red[tid], red[tid + s]);
        __syncthreads();
    }
    const float th = red[0] - MARGIN;
    if (tid == 0) nsurv = 0;
    __syncthreads();
    for (int t = tid; t < c; t += 256) {
        int2 e = cand[(size_t)i * CAP + t];
        if (__int_as_float(e.y) >= th) {
            int p = atomicAdd(&nsurv, 1);
            if (p < 64) surv[p] = e.x;
        }
    }
    __syncthreads();
    const int ns = min(nsurv, 64);
    for (int u = w; u < ns; u += 4) {
        const int j = surv[u];
        double a = 0.0;
        for (int d = lane; d < DIM; d += 64)
            a += (double)Y[(size_t)i * DIM + d] * (double)X[(size_t)j * DIM + d];
#pragma unroll
        for (int o = 32; o > 0; o >>= 1)
            a += __shfl_down(a, o, 64);
        if (lane == 0) sprec[u] = a;
    }
    __syncthreads();
    if (tid == 0) {
        double mm = -1.0e300;
        for (int u = 0; u < ns; ++u) mm = fmax(mm, sprec[u]);
        double l = 0.0;
        for (int u = 0; u < ns; ++u) l += exp(sprec[u] - mm);
        for (int u = 0; u < ns; ++u) wgt[u] = (float)(exp(sprec[u] - mm) / l);
    }
    __syncthreads();
    for (int d = tid; d < DIM; d += 256) {
        float o = 0.f;
        for (int u = 0; u < ns; ++u) {
            _Float16 hv = *(const _Float16*)&Vh[(size_t)surv[u] * DIM + d];
            o += wgt[u] * (float)hv;
        }
        out[(size_t)i * DIM + d] = o;
    }
}

extern "C" void kernel_launch(void* const* d_in, const int* in_sizes, int n_in,
                              void* d_out, int out_size, void* d_ws, size_t ws_size,
                              hipStream_t stream) {
    const float* X  = (const float*)d_in[0];
    const float* wq = (const float*)d_in[1];
    const float* wk = (const float*)d_in[2];
    const float* wv = (const float*)d_in[3];
    float* out = (float*)d_out;

    char* ws = (char*)d_ws;
    const size_t MB = 1024 * 1024;
    u16*   Xh   = (u16*)(ws +   0 * MB);   // 16 MB
    u16*   Xl   = (u16*)(ws +  16 * MB);   // 16 MB
    u16*   Wqh  = (u16*)(ws +  32 * MB);   // 2 MB each
    u16*   Wql  = (u16*)(ws +  34 * MB);
    u16*   Wkh  = (u16*)(ws +  36 * MB);
    u16*   Wkl  = (u16*)(ws +  38 * MB);
    u16*   Wvth = (u16*)(ws +  40 * MB);
    float* Gt   = (float*)(ws + 42 * MB);  // 4 MB fp32 [c][d]
    u16*   Gth  = (u16*)(ws +  46 * MB);
    u16*   Gtl  = (u16*)(ws +  48 * MB);
    float* Y    = (float*)(ws + 64 * MB);  // 32 MB
    u16*   Yh   = (u16*)(ws +  96 * MB);   // 16 MB
    u16*   Vh   = (u16*)(ws + 112 * MB);   // 16 MB
    int*   cnt  = (int*)(ws + 128 * MB);   // 32 KB
    int2*  cand = (int2*)(ws + 129 * MB);  // 8192*256*8 = 16.8 MB

    hipMemsetAsync(cnt, 0, (size_t)NROWS * 4, stream);

    split2h<<<NROWS * DIM / 1024, 256, 0, stream>>>(X, Xh, Xl);
    split2h<<<DIM * DIM / 1024, 256, 0, stream>>>(wq, Wqh, Wql);
    split2h<<<DIM * DIM / 1024, 256, 0, stream>>>(wk, Wkh, Wkl);
    split_wvt<<<dim3(16, 16), 256, 0, stream>>>(wv, Wvth);

    g_gemm<<<dim3(8, 8), 256, 0, stream>>>(Wkh, Wkl, Wqh, Wql, Gt);
    split2h<<<DIM * DIM / 1024, 256, 0, stream>>>(Gt, Gth, Gtl);

    yv_gemm<<<256, 512, 0, stream>>>(Xh, Xl, Gth, Gtl, Wvth, Y, Yh, Vh);

    filter_kernel<<<1024, 512, 0, stream>>>(Yh, Xh, cnt, cand);

    finalize_kernel<<<NROWS, 256, 0, stream>>>(Y, X, Vh, cnt, cand, out);
}

// Round 2
// 657.744 us; speedup vs baseline: 1.0966x; 1.0966x over previous
//
#include <hip/hip_runtime.h>
#include <hip/hip_bf16.h>
#include <math.h>

#define NROWS 8192
#define DIM   1024
#define CAP   256
#define MARGIN 120.0f

using f16x8 = __attribute__((ext_vector_type(8))) _Float16;
using f32x4 = __attribute__((ext_vector_type(4))) float;
typedef unsigned short u16;
typedef unsigned int   u32;

#define AS1 __attribute__((address_space(1)))
#define AS3 __attribute__((address_space(3)))

// inline-asm LDS read: invisible to the compiler's LDS-alias waitcnt tracking,
// so no auto s_waitcnt vmcnt(0) is injected before it (the round-1 killer
// pattern). Ordering vs MFMA enforced by counted lgkmcnt + sched_barrier(0)
// (rule #18).
#define DS_READ_B128(dst, off) \
    asm volatile("ds_read_b128 %0, %1" : "=v"(dst) : "v"(off))

// ---------------- split fp32 array (len % 1024 == 0) into hi/lo fp16 planes ----
// fp16 2-split carries ~22 mantissa bits: hi + lo with lo = fp16(x - (float)hi).
__global__ __launch_bounds__(256) void split2h(const float* __restrict__ X,
                                               u16* __restrict__ H,
                                               u16* __restrict__ L) {
    const int idx = (blockIdx.x * 256 + threadIdx.x) * 4;
    float4 x = *(const float4*)&X[idx];
    float c[4] = {x.x, x.y, x.z, x.w};
    u16 h[4], l[4];
#pragma unroll
    for (int i = 0; i < 4; ++i) {
        _Float16 hh = (_Float16)c[i];
        float r = c[i] - (float)hh;
        _Float16 ll = (_Float16)r;
        h[i] = *(u16*)&hh; l[i] = *(u16*)&ll;
    }
    *(ushort4*)&H[idx] = make_ushort4(h[0], h[1], h[2], h[3]);
    *(ushort4*)&L[idx] = make_ushort4(l[0], l[1], l[2], l[3]);
}

// ---------------- transpose Wv, keep hi fp16 plane: Wvth[c][d] = f16(Wv[d][c]) -
__global__ __launch_bounds__(256) void split_wvt(const float* __restrict__ W,
                                                 u16* __restrict__ H) {
    __shared__ float t[64][65];
    const int k0 = blockIdx.x * 64, n0 = blockIdx.y * 64;
    const int c = threadIdx.x & 63, r4 = threadIdx.x >> 6;
#pragma unroll
    for (int i = 0; i < 16; ++i) {
        int k = r4 + i * 4;
        t[k][c] = W[(size_t)(k0 + k) * DIM + n0 + c];
    }
    __syncthreads();
#pragma unroll
    for (int i = 0; i < 16; ++i) {
        int n = r4 + i * 4;
        _Float16 hb = (_Float16)t[c][n];
        H[(n0 + n) * DIM + k0 + c] = *(u16*)&hb;
    }
}

// ---------------- OLD shared LDS-dbuf 128x128 NT fp16 GEMM engine (g_gemm only)
template<int NP>
__device__ __forceinline__ void gemm_lds(const u16* const (&Ap)[NP],
                                         const u16* const (&Bp)[NP],
                                         int row0, int col0, f32x4 (&acc)[4][4],
                                         short (&As)[2][2][4096], short (&Bs)[2][2][4096]) {
    const int tid = threadIdx.x;
    const int w = tid >> 6, lane = tid & 63;
    const int wy = w >> 1, wx = w & 1;
    const int quad = lane >> 4, r16 = lane & 15;

    const int    srow   = w * 32 + (lane >> 2);
    const int    schunk = (lane & 3) * 8;
    const size_t gA0 = (size_t)(row0 + srow) * DIM + schunk;
    const size_t gA1 = gA0 + (size_t)16 * DIM;
    const size_t gB0 = (size_t)(col0 + srow) * DIM + schunk;
    const size_t gB1 = gB0 + (size_t)16 * DIM;
    const int lds0 = (w * 32) * 32;
    const int lds1 = (w * 32 + 16) * 32;

    auto issue = [&](const u16* A, const u16* B, size_t k0, int buf) {
#pragma unroll
        for (int s = 0; s < 2; ++s) {
            const size_t ko = k0 + (size_t)s * 32;
            __builtin_amdgcn_global_load_lds((const AS1 u32*)(A + gA0 + ko), (AS3 u32*)&As[buf][s][lds0], 16, 0, 0);
            __builtin_amdgcn_global_load_lds((const AS1 u32*)(A + gA1 + ko), (AS3 u32*)&As[buf][s][lds1], 16, 0, 0);
            __builtin_amdgcn_global_load_lds((const AS1 u32*)(B + gB0 + ko), (AS3 u32*)&Bs[buf][s][lds0], 16, 0, 0);
            __builtin_amdgcn_global_load_lds((const AS1 u32*)(B + gB1 + ko), (AS3 u32*)&Bs[buf][s][lds1], 16, 0, 0);
        }
    };

    issue(Ap[0], Bp[0], 0, 0);

    int pp = 0;
#pragma unroll
    for (int p = 0; p < NP; ++p) {
        const u16* A = Ap[p];
        const u16* B = Bp[p];
        const u16* An = (p + 1 < NP) ? Ap[p + 1] : A;
        const u16* Bn = (p + 1 < NP) ? Bp[p + 1] : B;
        const bool more = (p + 1 < NP);
        for (int i = 0; i < 16; ++i) {
            __syncthreads();
            const int cur = pp, nxt = pp ^ 1;
            if (i < 15)      issue(A, B, (size_t)(i + 1) * 64, nxt);
            else if (more)   issue(An, Bn, 0, nxt);
#pragma unroll
            for (int s = 0; s < 2; ++s) {
                const short* AsC = As[cur][s];
                const short* BsC = Bs[cur][s];
                f16x8 af[4], bfr[4];
#pragma unroll
                for (int m = 0; m < 4; ++m)
                    af[m] = *(const f16x8*)&AsC[(wy * 64 + m * 16 + r16) * 32 + quad * 8];
#pragma unroll
                for (int n = 0; n < 4; ++n)
                    bfr[n] = *(const f16x8*)&BsC[(wx * 64 + n * 16 + r16) * 32 + quad * 8];
#pragma unroll
                for (int m = 0; m < 4; ++m)
#pragma unroll
                    for (int n = 0; n < 4; ++n)
                        acc[m][n] = __builtin_amdgcn_mfma_f32_16x16x32_f16(af[m], bfr[n], acc[m][n], 0, 0, 0);
            }
            pp ^= 1;
        }
    }
}

// ---------------- 256x256 NT fp16 engine, BK=32, 4-deep pipeline, v2 ----------
// v2 change vs round-1 (which regressed -20%, the m196 "coarse split" failure):
// inline-asm ds_reads + STAGGERED counted lgkmcnt. Per K-step:
//   issue 12 ds_read_b128 (af0-3, bf0-3, af4-7) -> issue prefetch stage ->
//   lgkmcnt(4) [first 8 landed] -> 16 MFMA (af4-7 still in flight) ->
//   lgkmcnt(0) -> 16 MFMA.
// LDS read latency now hides under the first MFMA cluster, and the asm reads
// are invisible to the waitcnt pass (no auto vmcnt(0) drain: the alias with
// global_load_lds is hidden). Counted vmcnt(8) + raw s_barrier per step keeps
// 2 K-steps of staging in flight across every barrier (T3/T4). Source
// pre-swizzle (proven round-1: bank conflicts 1.7e7 -> 0) unchanged.
template<int NP>
__device__ __forceinline__ void gemm256(const u16* const (&Ap)[NP],
                                        const u16* const (&Bp)[NP],
                                        int row0, int col0, f32x4 (&acc)[8][4],
                                        short (&As)[4][8192], short (&Bs)[4][8192]) {
    const int tid = threadIdx.x;
    const int w = tid >> 6, lane = tid & 63;
    const int wy = w >> 2, wx = w & 3;
    const int quad = lane >> 4, r16 = lane & 15;

    // staging map: wave w covers tile rows w*16..w*16+15 (and +128); LDS dest
    // linear (HW appends lane*16B), global source chunk pre-swizzled.
    const int srow   = w * 16 + (lane >> 2);
    const int schunk = ((lane & 3) ^ ((lane >> 3) & 3)) * 8;
    const size_t gA0 = (size_t)(row0 + srow) * DIM + schunk;
    const size_t gA1 = gA0 + (size_t)128 * DIM;
    const size_t gB0 = (size_t)(col0 + srow) * DIM + schunk;
    const size_t gB1 = gB0 + (size_t)128 * DIM;
    const int lds0 = w * 512;          // shorts
    const int lds1 = 4096 + w * 512;   // shorts

    auto stage = [&](int kt, int buf) {
        const u16* A = Ap[(NP > 1) ? (kt >> 5) : 0];
        const u16* B = Bp[(NP > 1) ? (kt >> 5) : 0];
        const size_t ko = (size_t)(kt & 31) * 32;
        __builtin_amdgcn_global_load_lds((const AS1 u32*)(A + gA0 + ko), (AS3 u32*)&As[buf][lds0], 16, 0, 0);
        __builtin_amdgcn_global_load_lds((const AS1 u32*)(A + gA1 + ko), (AS3 u32*)&As[buf][lds1], 16, 0, 0);
        __builtin_amdgcn_global_load_lds((const AS1 u32*)(B + gB0 + ko), (AS3 u32*)&Bs[buf][lds0], 16, 0, 0);
        __builtin_amdgcn_global_load_lds((const AS1 u32*)(B + gB1 + ko), (AS3 u32*)&Bs[buf][lds1], 16, 0, 0);
    };

    // read-side swizzled addresses (LDS byte offsets, buf 0)
    const int ccol = (quad ^ ((r16 >> 1) & 3)) * 8;
    const int arow = wy * 128 + r16;
    const int brow = wx * 64  + r16;
    u32 aA[8], aB[4];
#pragma unroll
    for (int m = 0; m < 8; ++m)
        aA[m] = (u32)(uintptr_t)&As[0][(arow + m * 16) * 32 + ccol];
#pragma unroll
    for (int n = 0; n < 4; ++n)
        aB[n] = (u32)(uintptr_t)&Bs[0][(brow + n * 16) * 32 + ccol];

    constexpr int NK = NP * 32;

    auto step = [&](int t) {
        const int buf = t & 3;
        const u32 bo = (u32)buf * 16384u;
        f16x8 af[8], bf[4];
#pragma unroll
        for (int m = 0; m < 4; ++m) DS_READ_B128(af[m], aA[m] + bo);
#pragma unroll
        for (int n = 0; n < 4; ++n) DS_READ_B128(bf[n], aB[n] + bo);
#pragma unroll
        for (int m = 4; m < 8; ++m) DS_READ_B128(af[m], aA[m] + bo);
        if (t < NK - 3) stage(t + 3, (t + 3) & 3);     // VMEM issue overlaps DS latency
        asm volatile("s_waitcnt lgkmcnt(4)");           // af0-3, bf0-3 landed
        __builtin_amdgcn_sched_barrier(0);              // rule #18: pin MFMA below wait
        __builtin_amdgcn_s_setprio(1);
#pragma unroll
        for (int m = 0; m < 4; ++m)
#pragma unroll
            for (int n = 0; n < 4; ++n)
                acc[m][n] = __builtin_amdgcn_mfma_f32_16x16x32_f16(af[m], bf[n], acc[m][n], 0, 0, 0);
        __builtin_amdgcn_s_setprio(0);
        asm volatile("s_waitcnt lgkmcnt(0)");           // af4-7 landed
        __builtin_amdgcn_sched_barrier(0);
        __builtin_amdgcn_s_setprio(1);
#pragma unroll
        for (int m = 4; m < 8; ++m)
#pragma unroll
            for (int n = 0; n < 4; ++n)
                acc[m][n] = __builtin_amdgcn_mfma_f32_16x16x32_f16(af[m], bf[n], acc[m][n], 0, 0, 0);
        __builtin_amdgcn_s_setprio(0);
    };

    stage(0, 0); stage(1, 1); stage(2, 2);   // 12 loads in flight
#pragma unroll 1
    for (int t = 0; t < NK - 2; ++t) {
        // 12 outstanding -> wait to 8: oldest 4 (K-step t, issued 3 steps ago)
        // landed; 8 stay in flight ACROSS the barrier (never drain to 0).
        asm volatile("s_waitcnt vmcnt(8)");
        __builtin_amdgcn_s_barrier();
        step(t);
    }
    asm volatile("s_waitcnt vmcnt(4)");
    __builtin_amdgcn_s_barrier();
    step(NK - 2);
    asm volatile("s_waitcnt vmcnt(0)");
    __builtin_amdgcn_s_barrier();
    step(NK - 1);
}

// ---------------- Gt = Wk @ Wq^T (fp32 out, Gt[c][d] = (Wq Wk^T)[d][c]) --------
// fp16 2-split: 3 products {lh, hl, hh} carry ~22 bits (ll dropped, rel 2^-22).
__global__ __launch_bounds__(256) void g_gemm(const u16* __restrict__ Wkh, const u16* __restrict__ Wkl,
                                              const u16* __restrict__ Wqh, const u16* __restrict__ Wql,
                                              float* __restrict__ Gt) {
    __shared__ short As[2][2][4096], Bs[2][2][4096];
    const int tid = threadIdx.x, w = tid >> 6, lane = tid & 63;
    const int wy = w >> 1, wx = w & 1, quad = lane >> 4, r16 = lane & 15;
    const int row0 = blockIdx.y * 128, col0 = blockIdx.x * 128;
    const u16* const Ap[3] = { Wkl, Wkh, Wkh };   // lh, hl, hh (small -> large)
    const u16* const Bp[3] = { Wqh, Wql, Wqh };
    f32x4 acc[4][4] = {};
    gemm_lds<3>(Ap, Bp, row0, col0, acc, As, Bs);
#pragma unroll
    for (int m = 0; m < 4; ++m)
#pragma unroll
        for (int n = 0; n < 4; ++n)
#pragma unroll
            for (int reg = 0; reg < 4; ++reg) {
                const int row = row0 + wy * 64 + m * 16 + quad * 4 + reg;
                const int col = col0 + wx * 64 + n * 16 + r16;
                Gt[row * DIM + col] = acc[m][n][reg];
            }
}

// ---------------- part0: Y = X@G (fp32+fp16) ; part1: Vh = Xh@Wvt_h -----------
// 256 blocks of 512 thr = exactly 1 block/CU, one full-GPU round.
__global__ __launch_bounds__(512, 2) void yv_gemm(const u16* __restrict__ Xh, const u16* __restrict__ Xl,
                                                  const u16* __restrict__ Gth, const u16* __restrict__ Gtl,
                                                  const u16* __restrict__ Wvth,
                                                  float* __restrict__ Y, u16* __restrict__ Yh, u16* __restrict__ Vh) {
    __shared__ short As[4][8192], Bs[4][8192];
    const int tid = threadIdx.x, w = tid >> 6, lane = tid & 63;
    const int wy = w >> 2, wx = w & 3, quad = lane >> 4, r16 = lane & 15;
    const int id = blockIdx.x;
    const int part = id >> 7;              // 0: Y (K_eff=3072), 1: V (K=1024)
    const int within = id & 127;
    const int rowt = within >> 2, colt = within & 3;
    const int row0 = rowt * 256, col0 = colt * 256;
    f32x4 acc[8][4] = {};
    if (part == 0) {
        const u16* const Ap[3] = { Xl,  Xh,  Xh  };   // lh, hl, hh
        const u16* const Bp[3] = { Gth, Gtl, Gth };
        gemm256<3>(Ap, Bp, row0, col0, acc, As, Bs);
#pragma unroll
        for (int m = 0; m < 8; ++m)
#pragma unroll
            for (int n = 0; n < 4; ++n)
#pragma unroll
                for (int reg = 0; reg < 4; ++reg) {
                    const int row = row0 + wy * 128 + m * 16 + quad * 4 + reg;
                    const int col = col0 + wx * 64 + n * 16 + r16;
                    float v = acc[m][n][reg];
                    Y[(size_t)row * DIM + col] = v;
                    _Float16 hb = (_Float16)v;
                    Yh[(size_t)row * DIM + col] = *(u16*)&hb;
                }
    } else {
        const u16* const Ap[1] = { Xh };
        const u16* const Bp[1] = { Wvth };
        gemm256<1>(Ap, Bp, row0, col0, acc, As, Bs);
#pragma unroll
        for (int m = 0; m < 8; ++m)
#pragma unroll
            for (int n = 0; n < 4; ++n)
#pragma unroll
                for (int reg = 0; reg < 4; ++reg) {
                    const int row = row0 + wy * 128 + m * 16 + quad * 4 + reg;
                    const int col = col0 + wx * 64 + n * 16 + r16;
                    _Float16 hb = (_Float16)acc[m][n][reg];
                    Vh[(size_t)row * DIM + col] = *(u16*)&hb;
                }
    }
}

// ---------------- filter: S = Yh @ Xh^T (fp16), per-64col-group margin emit ----
// 1024 blocks of 512 thr = 32x32 tiles of 256x256. XCD map: 4 Xh col-panels
// pinned per XCD L2. Margin semantics identical to the proven version:
// group = one wave's 64 cols; the group max is always emitted.
__global__ __launch_bounds__(512, 2) void filter_kernel(const u16* __restrict__ Yhp,
                                                        const u16* __restrict__ Xhp,
                                                        int* __restrict__ cnt,
                                                        int2* __restrict__ cand) {
    __shared__ short As[4][8192], Bs[4][8192];
    const int tid = threadIdx.x, w = tid >> 6, lane = tid & 63;
    const int wy = w >> 2, wx = w & 3, quad = lane >> 4, r16 = lane & 15;
    const int id = blockIdx.x;
    const int xcd = id & 7, within = id >> 3;
    const int colt = (xcd << 2) | (within & 3);   // 0..31, 4 per XCD
    const int rowt = within >> 2;                  // 0..31
    const int row0 = rowt << 8, col0 = colt << 8;

    const u16* const Ap[1] = { Yhp };
    const u16* const Bp[1] = { Xhp };
    f32x4 acc[8][4] = {};
    gemm256<1>(Ap, Bp, row0, col0, acc, As, Bs);

    // per row: 64-col group max -> margin filter -> emit (mechanics proven)
#pragma unroll
    for (int m = 0; m < 8; ++m) {
#pragma unroll
        for (int reg = 0; reg < 4; ++reg) {
            float mx = fmaxf(fmaxf(acc[m][0][reg], acc[m][1][reg]),
                             fmaxf(acc[m][2][reg], acc[m][3][reg]));
            mx = fmaxf(mx, __shfl_xor(mx, 1, 64));
            mx = fmaxf(mx, __shfl_xor(mx, 2, 64));
            mx = fmaxf(mx, __shfl_xor(mx, 4, 64));
            mx = fmaxf(mx, __shfl_xor(mx, 8, 64));
            const float th = mx - MARGIN;
            const int row = row0 + wy * 128 + m * 16 + quad * 4 + reg;
#pragma unroll
            for (int n = 0; n < 4; ++n) {
                float s = acc[m][n][reg];
                if (s >= th) {
                    int pos = atomicAdd(&cnt[row], 1);
                    if (pos < CAP)
                        cand[(size_t)row * CAP + pos] =
                            make_int2(col0 + wx * 64 + n * 16 + r16, __float_as_int(s));
                }
            }
        }
    }
}

// ---------------- finalize: refilter, fp64 rescore via Y·X, softmax, gather Vh -
__global__ __launch_bounds__(256) void finalize_kernel(const float* __restrict__ Y,
                                                       const float* __restrict__ X,
                                                       const u16* __restrict__ Vh,
                                                       const int* __restrict__ cnt,
                                                       const int2* __restrict__ cand,
                                                       float* __restrict__ out) {
    const int i = blockIdx.x;
    const int tid = threadIdx.x;
    const int w = tid >> 6, lane = tid & 63;
    __shared__ float  red[256];
    __shared__ int    surv[64];
    __shared__ double sprec[64];
    __shared__ float  wgt[64];
    __shared__ int    nsurv;

    const int c = min(cnt[i], CAP);
    float m = -3.0e38f;
    for (int t = tid; t < c; t += 256)
        m = fmaxf(m, __int_as_float(cand[(size_t)i * CAP + t].y));
    red[tid] = m;
    __syncthreads();
    for (int s = 128; s > 0; s >>= 1) {
        if (tid < s) red[tid] = fmaxf(red[tid], red[tid + s]);
        __syncthreads();
    }
    const float th = red[0] - MARGIN;
    if (tid == 0) nsurv = 0;
    __syncthreads();
    for (int t = tid; t < c; t += 256) {
        int2 e = cand[(size_t)i * CAP + t];
        if (__int_as_float(e.y) >= th) {
            int p = atomicAdd(&nsurv, 1);
            if (p < 64) surv[p] = e.x;
        }
    }
    __syncthreads();
    const int ns = min(nsurv, 64);
    for (int u = w; u < ns; u += 4) {
        const int j = surv[u];
        double a = 0.0;
        for (int d = lane; d < DIM; d += 64)
            a += (double)Y[(size_t)i * DIM + d] * (double)X[(size_t)j * DIM + d];
#pragma unroll
        for (int o = 32; o > 0; o >>= 1)
            a += __shfl_down(a, o, 64);
        if (lane == 0) sprec[u] = a;
    }
    __syncthreads();
    if (tid == 0) {
        double mm = -1.0e300;
        for (int u = 0; u < ns; ++u) mm = fmax(mm, sprec[u]);
        double l = 0.0;
        for (int u = 0; u < ns; ++u) l += exp(sprec[u] - mm);
        for (int u = 0; u < ns; ++u) wgt[u] = (float)(exp(sprec[u] - mm) / l);
    }
    __syncthreads();
    for (int d = tid; d < DIM; d += 256) {
        float o = 0.f;
        for (int u = 0; u < ns; ++u) {
            _Float16 hv = *(const _Float16*)&Vh[(size_t)surv[u] * DIM + d];
            o += wgt[u] * (float)hv;
        }
        out[(size_t)i * DIM + d] = o;
    }
}

extern "C" void kernel_launch(void* const* d_in, const int* in_sizes, int n_in,
                              void* d_out, int out_size, void* d_ws, size_t ws_size,
                              hipStream_t stream) {
    const float* X  = (const float*)d_in[0];
    const float* wq = (const float*)d_in[1];
    const float* wk = (const float*)d_in[2];
    const float* wv = (const float*)d_in[3];
    float* out = (float*)d_out;

    char* ws = (char*)d_ws;
    const size_t MB = 1024 * 1024;
    u16*   Xh   = (u16*)(ws +   0 * MB);   // 16 MB
    u16*   Xl   = (u16*)(ws +  16 * MB);   // 16 MB
    u16*   Wqh  = (u16*)(ws +  32 * MB);   // 2 MB each
    u16*   Wql  = (u16*)(ws +  34 * MB);
    u16*   Wkh  = (u16*)(ws +  36 * MB);
    u16*   Wkl  = (u16*)(ws +  38 * MB);
    u16*   Wvth = (u16*)(ws +  40 * MB);
    float* Gt   = (float*)(ws + 42 * MB);  // 4 MB fp32 [c][d]
    u16*   Gth  = (u16*)(ws +  46 * MB);
    u16*   Gtl  = (u16*)(ws +  48 * MB);
    float* Y    = (float*)(ws + 64 * MB);  // 32 MB
    u16*   Yh   = (u16*)(ws +  96 * MB);   // 16 MB
    u16*   Vh   = (u16*)(ws + 112 * MB);   // 16 MB
    int*   cnt  = (int*)(ws + 128 * MB);   // 32 KB
    int2*  cand = (int2*)(ws + 129 * MB);  // 8192*256*8 = 16.8 MB

    hipMemsetAsync(cnt, 0, (size_t)NROWS * 4, stream);

    split2h<<<NROWS * DIM / 1024, 256, 0, stream>>>(X, Xh, Xl);
    split2h<<<DIM * DIM / 1024, 256, 0, stream>>>(wq, Wqh, Wql);
    split2h<<<DIM * DIM / 1024, 256, 0, stream>>>(wk, Wkh, Wkl);
    split_wvt<<<dim3(16, 16), 256, 0, stream>>>(wv, Wvth);

    g_gemm<<<dim3(8, 8), 256, 0, stream>>>(Wkh, Wkl, Wqh, Wql, Gt);
    split2h<<<DIM * DIM / 1024, 256, 0, stream>>>(Gt, Gth, Gtl);

    yv_gemm<<<256, 512, 0, stream>>>(Xh, Xl, Gth, Gtl, Wvth, Y, Yh, Vh);

    filter_kernel<<<1024, 512, 0, stream>>>(Yh, Xh, cnt, cand);

    finalize_kernel<<<NROWS, 256, 0, stream>>>(Y, X, Vh, cnt, cand, out);
}